// Round 1
// baseline (532.795 us; speedup 1.0000x reference)
//
#include <hip/hip_runtime.h>
#include <hip/hip_fp16.h>

typedef _Float16 f16;
typedef _Float16 f16x4 __attribute__((ext_vector_type(4)));
typedef _Float16 f16x8 __attribute__((ext_vector_type(8)));
typedef float f32x4 __attribute__((ext_vector_type(4)));

// Problem constants
// B=2, T=2048, D=2048, NH=16, HD=128, Q_LAT=1024, KV_LAT=512
#define BT 4096      // B*T rows
#define DMODEL 2048

__device__ __forceinline__ void gld16(const f16* g, f16* l) {
    __builtin_amdgcn_global_load_lds((const __attribute__((address_space(1))) void*)g,
                                     (__attribute__((address_space(3))) void*)l, 16, 0, 0);
}

// ---------------------------------------------------------------- fp32 -> fp16
__global__ void k_cvt(const float* __restrict__ s, f16* __restrict__ d, int n4) {
    int i = blockIdx.x * 256 + threadIdx.x;
    if (i < n4) {
        float4 v = ((const float4*)s)[i];
        f16x4 h;
        h[0] = (f16)v.x; h[1] = (f16)v.y; h[2] = (f16)v.z; h[3] = (f16)v.w;
        ((f16x4*)d)[i] = h;
    }
}

// ---------------------------------------------------------------- GEMM: C[M,N] = A[M,K] @ B[N,K]^T
// m97 structure: 128x128 tile, BK=32, global_load_lds width 16, 16x16x32 f16 MFMA.
template <typename CT>
__global__ __launch_bounds__(256, 2) void k_gemm_bt(const f16* __restrict__ A,
                                                    const f16* __restrict__ Bm,
                                                    CT* __restrict__ C,
                                                    int M, int N, int K) {
    __shared__ f16 Als[128 * 32];
    __shared__ f16 Bls[128 * 32];
    const int tid = threadIdx.x;
    const int w = tid >> 6, l = tid & 63;
    const int quad = l >> 4, ln = l & 15;
    const int m0 = blockIdx.y * 128, n0 = blockIdx.x * 128;
    const int wm = (w >> 1) * 64, wn = (w & 1) * 64;
    const int srow = l >> 2;          // row within 16-row staging chunk
    const int scol = (l & 3) * 8;     // k-offset within 32-wide tile

    f32x4 acc[4][4];
#pragma unroll
    for (int i = 0; i < 4; ++i)
#pragma unroll
        for (int j = 0; j < 4; ++j)
#pragma unroll
            for (int r = 0; r < 4; ++r) acc[i][j][r] = 0.f;

    for (int k0 = 0; k0 < K; k0 += 32) {
#pragma unroll
        for (int c = 0; c < 2; ++c) {
            const int ch = w + 4 * c;  // 0..7, 16 rows each
            gld16(A + (size_t)(m0 + ch * 16 + srow) * K + (k0 + scol), &Als[ch * 512]);
            gld16(Bm + (size_t)(n0 + ch * 16 + srow) * K + (k0 + scol), &Bls[ch * 512]);
        }
        __syncthreads();
        f16x8 af[4], bf[4];
#pragma unroll
        for (int i = 0; i < 4; ++i) af[i] = *(const f16x8*)&Als[(wm + 16 * i + ln) * 32 + quad * 8];
#pragma unroll
        for (int j = 0; j < 4; ++j) bf[j] = *(const f16x8*)&Bls[(wn + 16 * j + ln) * 32 + quad * 8];
#pragma unroll
        for (int i = 0; i < 4; ++i)
#pragma unroll
            for (int j = 0; j < 4; ++j)
                acc[i][j] = __builtin_amdgcn_mfma_f32_16x16x32_f16(af[i], bf[j], acc[i][j], 0, 0, 0);
        __syncthreads();
    }
    // epilogue: C layout col=lane&15, row=quad*4+reg
#pragma unroll
    for (int i = 0; i < 4; ++i)
#pragma unroll
        for (int j = 0; j < 4; ++j) {
            const int row = m0 + wm + 16 * i + quad * 4;
            const int col = n0 + wn + 16 * j + ln;
#pragma unroll
            for (int r = 0; r < 4; ++r) C[(size_t)(row + r) * N + col] = (CT)acc[i][j][r];
        }
}

// ---------------------------------------------------------------- RMSNorm + RoPE (in place), one wave per (row, head)
// lane i owns dims i and i+64 -> rotate_half is lane-local. sd folded into q.
__global__ __launch_bounds__(256) void k_norm_rope(f16* __restrict__ q, f16* __restrict__ k,
                                                   const float* __restrict__ qw,
                                                   const float* __restrict__ kw) {
    const int gw = blockIdx.x * 4 + (threadIdx.x >> 6);   // 0 .. 2*65536
    const int l = threadIdx.x & 63;
    const int which = gw >> 16;                           // 0=q, 1=k
    const int rh = gw & 65535;
    const int row = rh >> 4, h = rh & 15;
    f16* p = which ? k : q;
    const float* wp = which ? kw : qw;
    const float scale = which ? 1.0f : 0.08838834764831843f;  // 1/sqrt(128)
    const size_t base = (size_t)row * DMODEL + h * 128;
    float xa = (float)p[base + l];
    float xb = (float)p[base + 64 + l];
    float ss = xa * xa + xb * xb;
#pragma unroll
    for (int off = 32; off > 0; off >>= 1) ss += __shfl_xor(ss, off);
    const float rms = rsqrtf(ss * (1.0f / 128.0f) + 1e-6f);
    const float na = xa * rms * wp[l];
    const float nb = xb * rms * wp[64 + l];
    const int t = row & 2047;
    const float freq = __expf((float)l * -0.1439115683121279f);  // ln(10000)/64
    const float ang = (float)t * freq;
    const float c = cosf(ang), s = sinf(ang);
    p[base + l]      = (f16)((na * c - nb * s) * scale);
    p[base + 64 + l] = (f16)((nb * c + na * s) * scale);
}

// ---------------------------------------------------------------- V transpose: (b,t,h*128+d) -> vt[(b*2048 + h*128+d)*2048 + t]
__global__ __launch_bounds__(256) void k_transpose_v(const f16* __restrict__ src, f16* __restrict__ dst) {
    __shared__ f16 tile[64][68];
    const int t0 = blockIdx.x * 64, c0 = blockIdx.y * 64, b = blockIdx.z;
    const int tid = threadIdx.x;
#pragma unroll
    for (int it = 0; it < 4; ++it) {
        int idx = it * 256 + tid;             // 0..1023 chunks of 4
        int r = idx >> 4, c4 = (idx & 15) * 4;
        f16x4 v = *(const f16x4*)&src[(size_t)(b * 2048 + t0 + r) * DMODEL + c0 + c4];
        tile[r][c4] = v[0]; tile[r][c4 + 1] = v[1]; tile[r][c4 + 2] = v[2]; tile[r][c4 + 3] = v[3];
    }
    __syncthreads();
#pragma unroll
    for (int it = 0; it < 4; ++it) {
        int idx = it * 256 + tid;
        int rr = idx >> 4, cc4 = (idx & 15) * 4;
        f16x4 v;
        v[0] = tile[cc4][rr]; v[1] = tile[cc4 + 1][rr]; v[2] = tile[cc4 + 2][rr]; v[3] = tile[cc4 + 3][rr];
        *(f16x4*)&dst[(size_t)(b * 2048 + c0 + rr) * 2048 + t0 + cc4] = v;
    }
}

// ---------------------------------------------------------------- flash attention, causal
// grid: (T/64, NH, B), 256 threads = 4 waves x 16 q-rows.
__global__ __launch_bounds__(256, 2) void k_flash(const f16* __restrict__ Q, const f16* __restrict__ K,
                                                  const f16* __restrict__ Vt, f16* __restrict__ O) {
    __shared__ f16 Kl[64 * 136];   // [t_k][d], stride 136 (16B-aligned, 2-way banks)
    __shared__ f16 Vl[128 * 72];   // [d][t_k], stride 72
    __shared__ f16 Pl[4 * 16 * 80];// per-wave P: [q][t_k], stride 80
    const int mt = blockIdx.x, h = blockIdx.y, b = blockIdx.z;
    const int tid = threadIdx.x, w = tid >> 6, l = tid & 63;
    const int quad = l >> 4, ln = l & 15;

    f16x8 qf[4];
    {
        const int tq = mt * 64 + w * 16 + ln;
        const f16* qp = Q + (size_t)(b * 2048 + tq) * DMODEL + h * 128 + quad * 8;
#pragma unroll
        for (int kc = 0; kc < 4; ++kc) qf[kc] = *(const f16x8*)(qp + kc * 32);
    }
    f32x4 oacc[8];
    float m_r[4], l_r[4];
#pragma unroll
    for (int ot = 0; ot < 8; ++ot)
#pragma unroll
        for (int r = 0; r < 4; ++r) oacc[ot][r] = 0.f;
#pragma unroll
    for (int r = 0; r < 4; ++r) { m_r[r] = -INFINITY; l_r[r] = 0.f; }

    for (int j = 0; j <= mt; ++j) {
        const f16* kg = K + (size_t)(b * 2048 + j * 64) * DMODEL + h * 128;
        const f16* vg = Vt + (size_t)(b * 2048 + h * 128) * 2048 + j * 64;
#pragma unroll
        for (int it = 0; it < 4; ++it) {
            int idx = it * 256 + tid;
            int kr = idx >> 4, kc8 = (idx & 15) * 8;
            *(f16x8*)&Kl[kr * 136 + kc8] = *(const f16x8*)(kg + (size_t)kr * DMODEL + kc8);
            int vd = idx >> 3, vt8 = (idx & 7) * 8;
            *(f16x8*)&Vl[vd * 72 + vt8] = *(const f16x8*)(vg + (size_t)vd * 2048 + vt8);
        }
        __syncthreads();
        // S = Q K^T  (16 q-rows x 64 k-cols per wave)
        f32x4 sacc[4];
#pragma unroll
        for (int nt = 0; nt < 4; ++nt)
#pragma unroll
            for (int r = 0; r < 4; ++r) sacc[nt][r] = 0.f;
#pragma unroll
        for (int nt = 0; nt < 4; ++nt)
#pragma unroll
            for (int kc = 0; kc < 4; ++kc) {
                f16x8 kf = *(const f16x8*)&Kl[(nt * 16 + ln) * 136 + kc * 32 + quad * 8];
                sacc[nt] = __builtin_amdgcn_mfma_f32_16x16x32_f16(qf[kc], kf, sacc[nt], 0, 0, 0);
            }
        if (j == mt) {  // diagonal tile: causal mask
#pragma unroll
            for (int nt = 0; nt < 4; ++nt) {
                const int tk = nt * 16 + ln;
                const int tq_ = w * 16 + quad * 4;
#pragma unroll
                for (int r = 0; r < 4; ++r)
                    if (tk > tq_ + r) sacc[nt][r] = -INFINITY;
            }
        }
        // online softmax; row r of quad lives in 16-lane group (shfl_xor 1,2,4,8)
        float alpha[4];
#pragma unroll
        for (int r = 0; r < 4; ++r) {
            float mx = fmaxf(fmaxf(sacc[0][r], sacc[1][r]), fmaxf(sacc[2][r], sacc[3][r]));
#pragma unroll
            for (int off = 8; off > 0; off >>= 1) mx = fmaxf(mx, __shfl_xor(mx, off));
            const float mn = fmaxf(m_r[r], mx);
            alpha[r] = __expf(m_r[r] - mn);
            m_r[r] = mn;
            float s0 = 0.f;
#pragma unroll
            for (int nt = 0; nt < 4; ++nt) {
                float pv = __expf(sacc[nt][r] - mn);
                sacc[nt][r] = pv;
                s0 += pv;
            }
#pragma unroll
            for (int off = 8; off > 0; off >>= 1) s0 += __shfl_xor(s0, off);
            l_r[r] = l_r[r] * alpha[r] + s0;
        }
#pragma unroll
        for (int ot = 0; ot < 8; ++ot)
#pragma unroll
            for (int r = 0; r < 4; ++r) oacc[ot][r] *= alpha[r];
        // P: C-layout -> LDS -> A-layout
        f16* pl = &Pl[w * 16 * 80];
#pragma unroll
        for (int nt = 0; nt < 4; ++nt)
#pragma unroll
            for (int r = 0; r < 4; ++r)
                pl[(quad * 4 + r) * 80 + nt * 16 + ln] = (f16)sacc[nt][r];
        // O += P @ V
#pragma unroll
        for (int kc2 = 0; kc2 < 2; ++kc2) {
            f16x8 pf = *(const f16x8*)&pl[ln * 80 + kc2 * 32 + quad * 8];
#pragma unroll
            for (int ot = 0; ot < 8; ++ot) {
                f16x8 vf = *(const f16x8*)&Vl[(ot * 16 + ln) * 72 + kc2 * 32 + quad * 8];
                oacc[ot] = __builtin_amdgcn_mfma_f32_16x16x32_f16(pf, vf, oacc[ot], 0, 0, 0);
            }
        }
        __syncthreads();
    }
    float inv[4];
#pragma unroll
    for (int r = 0; r < 4; ++r) inv[r] = 1.0f / l_r[r];
    const int trow = mt * 64 + w * 16 + quad * 4;
#pragma unroll
    for (int ot = 0; ot < 8; ++ot)
#pragma unroll
        for (int r = 0; r < 4; ++r)
            O[(size_t)(b * 2048 + trow + r) * DMODEL + h * 128 + ot * 16 + ln] = (f16)(oacc[ot][r] * inv[r]);
}

// ----------------------------------------------------------------
extern "C" void kernel_launch(void* const* d_in, const int* in_sizes, int n_in,
                              void* d_out, int out_size, void* d_ws, size_t ws_size,
                              hipStream_t stream) {
    const float* x    = (const float*)d_in[0];
    // d_in[1] = attn_mask (exact causal mask) -- implemented in-kernel, unused
    const float* qaw  = (const float*)d_in[2];
    const float* qbw  = (const float*)d_in[3];
    const float* kvaw = (const float*)d_in[4];
    const float* kbw  = (const float*)d_in[5];
    const float* vbw  = (const float*)d_in[6];
    const float* ow   = (const float*)d_in[7];
    const float* qnw  = (const float*)d_in[8];
    const float* knw  = (const float*)d_in[9];
    float* out = (float*)d_out;

    char* p = (char*)d_ws;
    auto alloc = [&](size_t elems) { f16* r = (f16*)p; p += elems * sizeof(f16); return r; };
    f16* xb   = alloc((size_t)BT * 2048);   // also reused as vt after GEMM3
    f16* wqa  = alloc((size_t)1024 * 2048);
    f16* wqb  = alloc((size_t)2048 * 1024);
    f16* wkva = alloc((size_t)512 * 2048);
    f16* wkb  = alloc((size_t)2048 * 512);
    f16* wvb  = alloc((size_t)2048 * 512);
    f16* wo   = alloc((size_t)2048 * 2048);
    f16* qlat = alloc((size_t)BT * 1024);   // also reused as kvb (2.1M <= 4.2M)
    f16* qpre = alloc((size_t)BT * 2048);
    f16* kpre = alloc((size_t)BT * 2048);
    f16* vpre = alloc((size_t)BT * 2048);   // also reused as attn output
    f16* vt   = xb;
    f16* kvb  = qlat;
    f16* attn = vpre;

    auto cvt = [&](const float* s, f16* d, size_t n) {
        int n4 = (int)(n / 4);
        k_cvt<<<(n4 + 255) / 256, 256, 0, stream>>>(s, d, n4);
    };
    cvt(x,    xb,   (size_t)BT * 2048);
    cvt(qaw,  wqa,  (size_t)1024 * 2048);
    cvt(qbw,  wqb,  (size_t)2048 * 1024);
    cvt(kvaw, wkva, (size_t)512 * 2048);
    cvt(kbw,  wkb,  (size_t)2048 * 512);
    cvt(vbw,  wvb,  (size_t)2048 * 512);
    cvt(ow,   wo,   (size_t)2048 * 2048);

    dim3 blk(256);
    // q = (x @ q_a^T) @ q_b^T
    k_gemm_bt<f16><<<dim3(1024 / 128, BT / 128), blk, 0, stream>>>(xb, wqa, qlat, BT, 1024, 2048);
    k_gemm_bt<f16><<<dim3(2048 / 128, BT / 128), blk, 0, stream>>>(qlat, wqb, qpre, BT, 2048, 1024);
    // kv = x @ kv_a^T ; k = kv @ k_b^T ; v = kv @ v_b^T
    k_gemm_bt<f16><<<dim3(512 / 128, BT / 128), blk, 0, stream>>>(xb, wkva, kvb, BT, 512, 2048);
    k_gemm_bt<f16><<<dim3(2048 / 128, BT / 128), blk, 0, stream>>>(kvb, wkb, kpre, BT, 2048, 512);
    k_gemm_bt<f16><<<dim3(2048 / 128, BT / 128), blk, 0, stream>>>(kvb, wvb, vpre, BT, 2048, 512);
    // rmsnorm + rope (in place; sd folded into q)
    k_norm_rope<<<32768, 256, 0, stream>>>(qpre, kpre, qnw, knw);
    // v -> (b, h, d, t) for contiguous PV B-fragments
    k_transpose_v<<<dim3(32, 32, 2), 256, 0, stream>>>(vpre, vt);
    // flash attention
    k_flash<<<dim3(32, 16, 2), 256, 0, stream>>>(qpre, kpre, vt, attn);
    // out = attn @ o_w^T  (fp32 out)
    k_gemm_bt<float><<<dim3(2048 / 128, BT / 128), blk, 0, stream>>>(attn, wo, out, BT, 2048, 2048);
}

// Round 2
// 518.601 us; speedup vs baseline: 1.0274x; 1.0274x over previous
//
#include <hip/hip_runtime.h>
#include <hip/hip_fp16.h>

typedef _Float16 f16;
typedef _Float16 f16x4 __attribute__((ext_vector_type(4)));
typedef _Float16 f16x8 __attribute__((ext_vector_type(8)));
typedef float f32x4 __attribute__((ext_vector_type(4)));

// B=2, T=2048, D=2048, NH=16, HD=128, Q_LAT=1024, KV_LAT=512
#define BT 4096
#define DMODEL 2048

__device__ __forceinline__ void gld16(const f16* g, f16* l) {
    __builtin_amdgcn_global_load_lds((const __attribute__((address_space(1))) void*)g,
                                     (__attribute__((address_space(3))) void*)l, 16, 0, 0);
}

// ---------------------------------------------------------------- fp32 -> fp16
__global__ void k_cvt(const float* __restrict__ s, f16* __restrict__ d, int n4) {
    int i = blockIdx.x * 256 + threadIdx.x;
    if (i < n4) {
        float4 v = ((const float4*)s)[i];
        f16x4 h;
        h[0] = (f16)v.x; h[1] = (f16)v.y; h[2] = (f16)v.z; h[3] = (f16)v.w;
        ((f16x4*)d)[i] = h;
    }
}

// ---------------------------------------------------------------- GEMM: C[M,N] = A[M,K] @ B[N,K]^T
// m97 structure + LDS-repacked coalesced epilogue.
template <typename CT>
__global__ __launch_bounds__(256, 2) void k_gemm_bt(const f16* __restrict__ A,
                                                    const f16* __restrict__ Bm,
                                                    CT* __restrict__ C,
                                                    int M, int N, int K) {
    __shared__ __align__(16) char smem[16384];
    f16* Als = (f16*)smem;
    f16* Bls = (f16*)(smem + 8192);
    const int tid = threadIdx.x;
    const int w = tid >> 6, l = tid & 63;
    const int quad = l >> 4, ln = l & 15;
    const int m0 = blockIdx.y * 128, n0 = blockIdx.x * 128;
    const int wm = (w >> 1) * 64, wn = (w & 1) * 64;
    const int srow = l >> 2;
    const int scol = (l & 3) * 8;

    f32x4 acc[4][4];
#pragma unroll
    for (int i = 0; i < 4; ++i)
#pragma unroll
        for (int j = 0; j < 4; ++j)
#pragma unroll
            for (int r = 0; r < 4; ++r) acc[i][j][r] = 0.f;

    for (int k0 = 0; k0 < K; k0 += 32) {
#pragma unroll
        for (int c = 0; c < 2; ++c) {
            const int ch = w + 4 * c;
            gld16(A + (size_t)(m0 + ch * 16 + srow) * K + (k0 + scol), &Als[ch * 512]);
            gld16(Bm + (size_t)(n0 + ch * 16 + srow) * K + (k0 + scol), &Bls[ch * 512]);
        }
        __syncthreads();
        f16x8 af[4], bf[4];
#pragma unroll
        for (int i = 0; i < 4; ++i) af[i] = *(const f16x8*)&Als[(wm + 16 * i + ln) * 32 + quad * 8];
#pragma unroll
        for (int j = 0; j < 4; ++j) bf[j] = *(const f16x8*)&Bls[(wn + 16 * j + ln) * 32 + quad * 8];
#pragma unroll
        for (int i = 0; i < 4; ++i)
#pragma unroll
            for (int j = 0; j < 4; ++j)
                acc[i][j] = __builtin_amdgcn_mfma_f32_16x16x32_f16(af[i], bf[j], acc[i][j], 0, 0, 0);
        __syncthreads();
    }
    // epilogue: repack 32 rows at a time through LDS for coalesced stores
    const int p_w = (w >> 1) ? 16 : 0;
#pragma unroll
    for (int i = 0; i < 4; ++i) {
        if constexpr (sizeof(CT) == 2) {
            f16* Cs = (f16*)smem;  // [32][136]
#pragma unroll
            for (int j = 0; j < 4; ++j)
#pragma unroll
                for (int r = 0; r < 4; ++r)
                    Cs[(p_w + quad * 4 + r) * 136 + wn + 16 * j + ln] = (f16)acc[i][j][r];
            __syncthreads();
#pragma unroll
            for (int k2 = 0; k2 < 2; ++k2) {
                int idx = k2 * 256 + tid;
                int pr = idx >> 4, c = idx & 15;
                int rg = m0 + 16 * i + (pr & 15) + ((pr & 16) ? 64 : 0);
                *(f16x8*)&C[(size_t)rg * N + n0 + c * 8] = *(const f16x8*)&Cs[pr * 136 + c * 8];
            }
        } else {
            float* Cs = (float*)smem;  // [32][128]
#pragma unroll
            for (int j = 0; j < 4; ++j)
#pragma unroll
                for (int r = 0; r < 4; ++r)
                    Cs[(p_w + quad * 4 + r) * 128 + wn + 16 * j + ln] = acc[i][j][r];
            __syncthreads();
#pragma unroll
            for (int k2 = 0; k2 < 4; ++k2) {
                int idx = k2 * 256 + tid;
                int pr = idx >> 5, c = idx & 31;
                int rg = m0 + 16 * i + (pr & 15) + ((pr & 16) ? 64 : 0);
                *(float4*)&C[(size_t)rg * N + n0 + c * 4] = *(const float4*)&Cs[pr * 128 + c * 4];
            }
        }
        __syncthreads();
    }
}

// ---------------------------------------------------------------- RMSNorm + RoPE (in place)
__global__ __launch_bounds__(256) void k_norm_rope(f16* __restrict__ q, f16* __restrict__ k,
                                                   const float* __restrict__ qw,
                                                   const float* __restrict__ kw) {
    const int gw = blockIdx.x * 4 + (threadIdx.x >> 6);
    const int l = threadIdx.x & 63;
    const int which = gw >> 16;
    const int rh = gw & 65535;
    const int row = rh >> 4, h = rh & 15;
    f16* p = which ? k : q;
    const float* wp = which ? kw : qw;
    const float scale = which ? 1.0f : 0.08838834764831843f;  // 1/sqrt(128) folded into q
    const size_t base = (size_t)row * DMODEL + h * 128;
    float xa = (float)p[base + l];
    float xb = (float)p[base + 64 + l];
    float ss = xa * xa + xb * xb;
#pragma unroll
    for (int off = 32; off > 0; off >>= 1) ss += __shfl_xor(ss, off);
    const float rms = rsqrtf(ss * (1.0f / 128.0f) + 1e-6f);
    const float na = xa * rms * wp[l];
    const float nb = xb * rms * wp[64 + l];
    const int t = row & 2047;
    const float freq = __expf((float)l * -0.1439115683121279f);  // ln(10000)/64
    const float ang = (float)t * freq;
    const float c = cosf(ang), s = sinf(ang);
    p[base + l]      = (f16)((na * c - nb * s) * scale);
    p[base + 64 + l] = (f16)((nb * c + na * s) * scale);
}

// ---------------------------------------------------------------- V transpose -> vt[(b*2048 + h*128+d)*2048 + t]
__global__ __launch_bounds__(256) void k_transpose_v(const f16* __restrict__ src, f16* __restrict__ dst) {
    __shared__ f16 tile[64][68];
    const int t0 = blockIdx.x * 64, c0 = blockIdx.y * 64, b = blockIdx.z;
    const int tid = threadIdx.x;
#pragma unroll
    for (int it = 0; it < 4; ++it) {
        int idx = it * 256 + tid;
        int r = idx >> 4, c4 = (idx & 15) * 4;
        f16x4 v = *(const f16x4*)&src[(size_t)(b * 2048 + t0 + r) * DMODEL + c0 + c4];
        tile[r][c4] = v[0]; tile[r][c4 + 1] = v[1]; tile[r][c4 + 2] = v[2]; tile[r][c4 + 3] = v[3];
    }
    __syncthreads();
#pragma unroll
    for (int it = 0; it < 4; ++it) {
        int idx = it * 256 + tid;
        int rr = idx >> 4, cc4 = (idx & 15) * 4;
        f16x4 v;
        v[0] = tile[cc4][rr]; v[1] = tile[cc4 + 1][rr]; v[2] = tile[cc4 + 2][rr]; v[3] = tile[cc4 + 3][rr];
        *(f16x4*)&dst[(size_t)(b * 2048 + c0 + rr) * 2048 + t0 + cc4] = v;
    }
}

// ---------------------------------------------------------------- flash attention, causal, BM=128 BN=64
// grid: (16, NH, B), mt = 15 - bx (heavy blocks dispatch first). 4 waves x 32 q-rows.
__global__ __launch_bounds__(256, 2) void k_flash(const f16* __restrict__ Q, const f16* __restrict__ K,
                                                  const f16* __restrict__ Vt, f16* __restrict__ O) {
    __shared__ f16 sm[64 * 136 + 128 * 72 + 4 * 32 * 80];
    f16* Kl = sm;                    // [64][136]
    f16* Vl = sm + 64 * 136;         // [128][72]
    f16* Pl = Vl + 128 * 72;         // 4 waves x [32][80]
    const int mt = 15 - blockIdx.x, h = blockIdx.y, b = blockIdx.z;
    const int tid = threadIdx.x, w = tid >> 6, l = tid & 63;
    const int quad = l >> 4, ln = l & 15;

    f16x8 qf[2][4];
#pragma unroll
    for (int mi = 0; mi < 2; ++mi) {
        const int tq = mt * 128 + w * 16 + mi * 64 + ln;
        const f16* qp = Q + (size_t)(b * 2048 + tq) * DMODEL + h * 128 + quad * 8;
#pragma unroll
        for (int kc = 0; kc < 4; ++kc) qf[mi][kc] = *(const f16x8*)(qp + kc * 32);
    }
    f32x4 oacc[2][8];
    float m_r[2][4], l_r[2][4];
#pragma unroll
    for (int mi = 0; mi < 2; ++mi) {
#pragma unroll
        for (int ot = 0; ot < 8; ++ot)
#pragma unroll
            for (int r = 0; r < 4; ++r) oacc[mi][ot][r] = 0.f;
#pragma unroll
        for (int r = 0; r < 4; ++r) { m_r[mi][r] = -INFINITY; l_r[mi][r] = 0.f; }
    }

    const int jend = 2 * mt + 2;
    const f16* kbase = K + (size_t)(b * 2048) * DMODEL + h * 128;
    const f16* vbase = Vt + (size_t)(b * 2048 + h * 128) * 2048;

    f16x8 kr[4], vr[4];
    {
#pragma unroll
        for (int c = 0; c < 4; ++c) {
            int idx = c * 256 + tid;
            kr[c] = *(const f16x8*)(kbase + (size_t)(idx >> 4) * DMODEL + (idx & 15) * 8);
            vr[c] = *(const f16x8*)(vbase + (size_t)(idx >> 3) * 2048 + (idx & 7) * 8);
        }
    }

    for (int j = 0; j < jend; ++j) {
        __syncthreads();  // prior iteration's LDS reads complete
#pragma unroll
        for (int c = 0; c < 4; ++c) {
            int idx = c * 256 + tid;
            *(f16x8*)&Kl[(idx >> 4) * 136 + (idx & 15) * 8] = kr[c];
            *(f16x8*)&Vl[(idx >> 3) * 72 + (idx & 7) * 8] = vr[c];
        }
        __syncthreads();
        if (j + 1 < jend) {  // prefetch next tile; loads fly during compute below
#pragma unroll
            for (int c = 0; c < 4; ++c) {
                int idx = c * 256 + tid;
                kr[c] = *(const f16x8*)(kbase + (size_t)((j + 1) * 64 + (idx >> 4)) * DMODEL + (idx & 15) * 8);
                vr[c] = *(const f16x8*)(vbase + (size_t)(idx >> 3) * 2048 + (j + 1) * 64 + (idx & 7) * 8);
            }
        }
        // S = Q K^T : share K fragments across both m-tiles
        f32x4 sacc[2][4];
#pragma unroll
        for (int mi = 0; mi < 2; ++mi)
#pragma unroll
            for (int nt = 0; nt < 4; ++nt)
#pragma unroll
                for (int r = 0; r < 4; ++r) sacc[mi][nt][r] = 0.f;
#pragma unroll
        for (int nt = 0; nt < 4; ++nt)
#pragma unroll
            for (int kc = 0; kc < 4; ++kc) {
                f16x8 kf = *(const f16x8*)&Kl[(nt * 16 + ln) * 136 + kc * 32 + quad * 8];
                sacc[0][nt] = __builtin_amdgcn_mfma_f32_16x16x32_f16(qf[0][kc], kf, sacc[0][nt], 0, 0, 0);
                sacc[1][nt] = __builtin_amdgcn_mfma_f32_16x16x32_f16(qf[1][kc], kf, sacc[1][nt], 0, 0, 0);
            }
        if (j >= 2 * mt) {  // diagonal tiles: causal mask
#pragma unroll
            for (int mi = 0; mi < 2; ++mi)
#pragma unroll
                for (int nt = 0; nt < 4; ++nt) {
                    const int tk = j * 64 + nt * 16 + ln;
                    const int tq = mt * 128 + w * 16 + mi * 64 + quad * 4;
#pragma unroll
                    for (int r = 0; r < 4; ++r)
                        if (tk > tq + r) sacc[mi][nt][r] = -INFINITY;
                }
        }
        f16* pw = &Pl[w * 32 * 80];
#pragma unroll
        for (int mi = 0; mi < 2; ++mi) {
#pragma unroll
            for (int r = 0; r < 4; ++r) {
                float mx = fmaxf(fmaxf(sacc[mi][0][r], sacc[mi][1][r]), fmaxf(sacc[mi][2][r], sacc[mi][3][r]));
#pragma unroll
                for (int off = 8; off > 0; off >>= 1) mx = fmaxf(mx, __shfl_xor(mx, off));
                const float mn = fmaxf(m_r[mi][r], mx);
                const float alpha = __expf(m_r[mi][r] - mn);
                m_r[mi][r] = mn;
                float s0 = 0.f;
#pragma unroll
                for (int nt = 0; nt < 4; ++nt) {
                    float pv = __expf(sacc[mi][nt][r] - mn);
                    s0 += pv;
                    pw[(mi * 16 + quad * 4 + r) * 80 + nt * 16 + ln] = (f16)pv;
                }
#pragma unroll
                for (int off = 8; off > 0; off >>= 1) s0 += __shfl_xor(s0, off);
                l_r[mi][r] = l_r[mi][r] * alpha + s0;
#pragma unroll
                for (int ot = 0; ot < 8; ++ot) oacc[mi][ot][r] *= alpha;
            }
        }
        // O += P @ V : share V fragments across both m-tiles
#pragma unroll
        for (int kc2 = 0; kc2 < 2; ++kc2) {
            f16x8 pf0 = *(const f16x8*)&pw[ln * 80 + kc2 * 32 + quad * 8];
            f16x8 pf1 = *(const f16x8*)&pw[(16 + ln) * 80 + kc2 * 32 + quad * 8];
#pragma unroll
            for (int ot = 0; ot < 8; ++ot) {
                f16x8 vf = *(const f16x8*)&Vl[(ot * 16 + ln) * 72 + kc2 * 32 + quad * 8];
                oacc[0][ot] = __builtin_amdgcn_mfma_f32_16x16x32_f16(pf0, vf, oacc[0][ot], 0, 0, 0);
                oacc[1][ot] = __builtin_amdgcn_mfma_f32_16x16x32_f16(pf1, vf, oacc[1][ot], 0, 0, 0);
            }
        }
    }
    // O epilogue through LDS for coalesced 16B stores
    float inv[2][4];
#pragma unroll
    for (int mi = 0; mi < 2; ++mi)
#pragma unroll
        for (int r = 0; r < 4; ++r) inv[mi][r] = 1.0f / l_r[mi][r];
    __syncthreads();
#pragma unroll
    for (int mi = 0; mi < 2; ++mi) {
#pragma unroll
        for (int ot = 0; ot < 8; ++ot)
#pragma unroll
            for (int r = 0; r < 4; ++r)
                sm[(w * 16 + quad * 4 + r) * 136 + ot * 16 + ln] = (f16)(oacc[mi][ot][r] * inv[mi][r]);
        __syncthreads();
#pragma unroll
        for (int k2 = 0; k2 < 4; ++k2) {
            int idx = k2 * 256 + tid;
            int row = idx >> 4, c = idx & 15;
            *(f16x8*)&O[(size_t)(b * 2048 + mt * 128 + mi * 64 + row) * DMODEL + h * 128 + c * 8] =
                *(const f16x8*)&sm[row * 136 + c * 8];
        }
        __syncthreads();
    }
}

// ----------------------------------------------------------------
extern "C" void kernel_launch(void* const* d_in, const int* in_sizes, int n_in,
                              void* d_out, int out_size, void* d_ws, size_t ws_size,
                              hipStream_t stream) {
    const float* x    = (const float*)d_in[0];
    const float* qaw  = (const float*)d_in[2];
    const float* qbw  = (const float*)d_in[3];
    const float* kvaw = (const float*)d_in[4];
    const float* kbw  = (const float*)d_in[5];
    const float* vbw  = (const float*)d_in[6];
    const float* ow   = (const float*)d_in[7];
    const float* qnw  = (const float*)d_in[8];
    const float* knw  = (const float*)d_in[9];
    float* out = (float*)d_out;

    char* p = (char*)d_ws;
    auto alloc = [&](size_t elems) { f16* r = (f16*)p; p += elems * sizeof(f16); return r; };
    f16* xb   = alloc((size_t)BT * 2048);
    f16* wqa  = alloc((size_t)1024 * 2048);
    f16* wqb  = alloc((size_t)2048 * 1024);
    f16* wkva = alloc((size_t)512 * 2048);
    f16* wkb  = alloc((size_t)2048 * 512);
    f16* wvb  = alloc((size_t)2048 * 512);
    f16* wo   = alloc((size_t)2048 * 2048);
    f16* qlat = alloc((size_t)BT * 1024);
    f16* qpre = alloc((size_t)BT * 2048);
    f16* kpre = alloc((size_t)BT * 2048);
    f16* vpre = alloc((size_t)BT * 2048);
    f16* vt   = xb;    // reuse after GEMMs consume xb
    f16* kvb  = qlat;  // reuse after GEMM2 consumes qlat
    f16* attn = vpre;  // reuse after transpose consumes vpre

    auto cvt = [&](const float* s, f16* d, size_t n) {
        int n4 = (int)(n / 4);
        k_cvt<<<(n4 + 255) / 256, 256, 0, stream>>>(s, d, n4);
    };
    cvt(x,    xb,   (size_t)BT * 2048);
    cvt(qaw,  wqa,  (size_t)1024 * 2048);
    cvt(qbw,  wqb,  (size_t)2048 * 1024);
    cvt(kvaw, wkva, (size_t)512 * 2048);
    cvt(kbw,  wkb,  (size_t)2048 * 512);
    cvt(vbw,  wvb,  (size_t)2048 * 512);
    cvt(ow,   wo,   (size_t)2048 * 2048);

    dim3 blk(256);
    k_gemm_bt<f16><<<dim3(1024 / 128, BT / 128), blk, 0, stream>>>(xb, wqa, qlat, BT, 1024, 2048);
    k_gemm_bt<f16><<<dim3(2048 / 128, BT / 128), blk, 0, stream>>>(qlat, wqb, qpre, BT, 2048, 1024);
    k_gemm_bt<f16><<<dim3(512 / 128, BT / 128), blk, 0, stream>>>(xb, wkva, kvb, BT, 512, 2048);
    k_gemm_bt<f16><<<dim3(2048 / 128, BT / 128), blk, 0, stream>>>(kvb, wkb, kpre, BT, 2048, 512);
    k_gemm_bt<f16><<<dim3(2048 / 128, BT / 128), blk, 0, stream>>>(kvb, wvb, vpre, BT, 2048, 512);
    k_norm_rope<<<32768, 256, 0, stream>>>(qpre, kpre, qnw, knw);
    k_transpose_v<<<dim3(32, 32, 2), 256, 0, stream>>>(vpre, vt);
    k_flash<<<dim3(16, 16, 2), 256, 0, stream>>>(qpre, kpre, vt, attn);
    k_gemm_bt<float><<<dim3(2048 / 128, BT / 128), blk, 0, stream>>>(attn, wo, out, BT, 2048, 2048);
}

// Round 3
// 472.163 us; speedup vs baseline: 1.1284x; 1.0984x over previous
//
#include <hip/hip_runtime.h>
#include <hip/hip_fp16.h>

typedef _Float16 f16;
typedef _Float16 f16x4 __attribute__((ext_vector_type(4)));
typedef _Float16 f16x8 __attribute__((ext_vector_type(8)));
typedef float f32x4 __attribute__((ext_vector_type(4)));

// B=2, T=2048, D=2048, NH=16, HD=128, Q_LAT=1024, KV_LAT=512
#define BT 4096
#define DMODEL 2048

__device__ __forceinline__ void gld16(const f16* g, f16* l) {
    __builtin_amdgcn_global_load_lds((const __attribute__((address_space(1))) void*)g,
                                     (__attribute__((address_space(3))) void*)l, 16, 0, 0);
}

// ---------------------------------------------------------------- fused fp32 -> fp16 (7 tensors, 1 launch)
struct Cvt7 {
    const float* s[7];
    f16* d[7];
    int off4[8];  // cumulative float4 counts
};
__global__ __launch_bounds__(256) void k_cvt7(Cvt7 c) {
    int i = blockIdx.x * 256 + threadIdx.x;
    if (i >= c.off4[7]) return;
    int seg = 0;
#pragma unroll
    for (int k = 1; k < 7; ++k) seg += (i >= c.off4[k]);
    int j = i - c.off4[seg];
    float4 v = ((const float4*)c.s[seg])[j];
    f16x4 h;
    h[0] = (f16)v.x; h[1] = (f16)v.y; h[2] = (f16)v.z; h[3] = (f16)v.w;
    ((f16x4*)c.d[seg])[j] = h;
}

// ---------------------------------------------------------------- GEMM core pieces (m97 structure)
// staging + MFMA main loop shared by all GEMM variants via macro-free duplication.

// plain: C[M,N] = A[M,K] @ B[N,K]^T
template <typename CT>
__global__ __launch_bounds__(256, 2) void k_gemm_bt(const f16* __restrict__ A,
                                                    const f16* __restrict__ Bm,
                                                    CT* __restrict__ C,
                                                    int M, int N, int K) {
    __shared__ __align__(16) char smem[16384];
    f16* Als = (f16*)smem;
    f16* Bls = (f16*)(smem + 8192);
    const int tid = threadIdx.x;
    const int w = tid >> 6, l = tid & 63;
    const int quad = l >> 4, ln = l & 15;
    const int m0 = blockIdx.y * 128, n0 = blockIdx.x * 128;
    const int wm = (w >> 1) * 64, wn = (w & 1) * 64;
    const int srow = l >> 2, scol = (l & 3) * 8;

    f32x4 acc[4][4];
#pragma unroll
    for (int i = 0; i < 4; ++i)
#pragma unroll
        for (int j = 0; j < 4; ++j)
#pragma unroll
            for (int r = 0; r < 4; ++r) acc[i][j][r] = 0.f;

    for (int k0 = 0; k0 < K; k0 += 32) {
#pragma unroll
        for (int c = 0; c < 2; ++c) {
            const int ch = w + 4 * c;
            gld16(A + (size_t)(m0 + ch * 16 + srow) * K + (k0 + scol), &Als[ch * 512]);
            gld16(Bm + (size_t)(n0 + ch * 16 + srow) * K + (k0 + scol), &Bls[ch * 512]);
        }
        __syncthreads();
        f16x8 af[4], bf[4];
#pragma unroll
        for (int i = 0; i < 4; ++i) af[i] = *(const f16x8*)&Als[(wm + 16 * i + ln) * 32 + quad * 8];
#pragma unroll
        for (int j = 0; j < 4; ++j) bf[j] = *(const f16x8*)&Bls[(wn + 16 * j + ln) * 32 + quad * 8];
#pragma unroll
        for (int i = 0; i < 4; ++i)
#pragma unroll
            for (int j = 0; j < 4; ++j)
                acc[i][j] = __builtin_amdgcn_mfma_f32_16x16x32_f16(af[i], bf[j], acc[i][j], 0, 0, 0);
        __syncthreads();
    }
    const int p_w = (w >> 1) ? 16 : 0;
#pragma unroll
    for (int i = 0; i < 4; ++i) {
        if constexpr (sizeof(CT) == 2) {
            f16* Cs = (f16*)smem;  // [32][136]
#pragma unroll
            for (int j = 0; j < 4; ++j)
#pragma unroll
                for (int r = 0; r < 4; ++r)
                    Cs[(p_w + quad * 4 + r) * 136 + wn + 16 * j + ln] = (f16)acc[i][j][r];
            __syncthreads();
#pragma unroll
            for (int k2 = 0; k2 < 2; ++k2) {
                int idx = k2 * 256 + tid;
                int pr = idx >> 4, c = idx & 15;
                int rg = m0 + 16 * i + (pr & 15) + ((pr & 16) ? 64 : 0);
                *(f16x8*)&C[(size_t)rg * N + n0 + c * 8] = *(const f16x8*)&Cs[pr * 136 + c * 8];
            }
        } else {
            float* Cs = (float*)smem;  // [32][128]
#pragma unroll
            for (int j = 0; j < 4; ++j)
#pragma unroll
                for (int r = 0; r < 4; ++r)
                    Cs[(p_w + quad * 4 + r) * 128 + wn + 16 * j + ln] = acc[i][j][r];
            __syncthreads();
#pragma unroll
            for (int k2 = 0; k2 < 4; ++k2) {
                int idx = k2 * 256 + tid;
                int pr = idx >> 5, c = idx & 31;
                int rg = m0 + 16 * i + (pr & 15) + ((pr & 16) ? 64 : 0);
                *(float4*)&C[(size_t)rg * N + n0 + c * 4] = *(const float4*)&Cs[pr * 128 + c * 4];
            }
        }
        __syncthreads();
    }
}

// dual-B / dual-C: cols < nsplit -> C0 (ld0), else C1 (ld1). Both f16.
__global__ __launch_bounds__(256, 2) void k_gemm_dual(const f16* __restrict__ A,
                                                      const f16* __restrict__ B0,
                                                      const f16* __restrict__ B1,
                                                      f16* __restrict__ C0, f16* __restrict__ C1,
                                                      int K, int nsplit, int ld0, int ld1) {
    __shared__ __align__(16) char smem[16384];
    f16* Als = (f16*)smem;
    f16* Bls = (f16*)(smem + 8192);
    const int tid = threadIdx.x;
    const int w = tid >> 6, l = tid & 63;
    const int quad = l >> 4, ln = l & 15;
    const int m0 = blockIdx.y * 128, n0 = blockIdx.x * 128;
    const int wm = (w >> 1) * 64, wn = (w & 1) * 64;
    const int srow = l >> 2, scol = (l & 3) * 8;
    const f16* Bm = (n0 < nsplit) ? B0 + (size_t)n0 * K : B1 + (size_t)(n0 - nsplit) * K;

    f32x4 acc[4][4];
#pragma unroll
    for (int i = 0; i < 4; ++i)
#pragma unroll
        for (int j = 0; j < 4; ++j)
#pragma unroll
            for (int r = 0; r < 4; ++r) acc[i][j][r] = 0.f;

    for (int k0 = 0; k0 < K; k0 += 32) {
#pragma unroll
        for (int c = 0; c < 2; ++c) {
            const int ch = w + 4 * c;
            gld16(A + (size_t)(m0 + ch * 16 + srow) * K + (k0 + scol), &Als[ch * 512]);
            gld16(Bm + (size_t)(ch * 16 + srow) * K + (k0 + scol), &Bls[ch * 512]);
        }
        __syncthreads();
        f16x8 af[4], bf[4];
#pragma unroll
        for (int i = 0; i < 4; ++i) af[i] = *(const f16x8*)&Als[(wm + 16 * i + ln) * 32 + quad * 8];
#pragma unroll
        for (int j = 0; j < 4; ++j) bf[j] = *(const f16x8*)&Bls[(wn + 16 * j + ln) * 32 + quad * 8];
#pragma unroll
        for (int i = 0; i < 4; ++i)
#pragma unroll
            for (int j = 0; j < 4; ++j)
                acc[i][j] = __builtin_amdgcn_mfma_f32_16x16x32_f16(af[i], bf[j], acc[i][j], 0, 0, 0);
        __syncthreads();
    }
    f16* Cd; int ldc, cb;
    if (n0 < nsplit) { Cd = C0; ldc = ld0; cb = n0; }
    else             { Cd = C1; ldc = ld1; cb = n0 - nsplit; }
    const int p_w = (w >> 1) ? 16 : 0;
    f16* Cs = (f16*)smem;  // [32][136]
#pragma unroll
    for (int i = 0; i < 4; ++i) {
#pragma unroll
        for (int j = 0; j < 4; ++j)
#pragma unroll
            for (int r = 0; r < 4; ++r)
                Cs[(p_w + quad * 4 + r) * 136 + wn + 16 * j + ln] = (f16)acc[i][j][r];
        __syncthreads();
#pragma unroll
        for (int k2 = 0; k2 < 2; ++k2) {
            int idx = k2 * 256 + tid;
            int pr = idx >> 4, c = idx & 15;
            int rg = m0 + 16 * i + (pr & 15) + ((pr & 16) ? 64 : 0);
            *(f16x8*)&Cd[(size_t)rg * ldc + cb + c * 8] = *(const f16x8*)&Cs[pr * 136 + c * 8];
        }
        __syncthreads();
    }
}

// k/v GEMM: cols<2048 -> kpre normal; cols>=2048 -> V written TRANSPOSED into vt[(b*2048+d)*2048 + t]
__global__ __launch_bounds__(256, 2) void k_gemm_kv(const f16* __restrict__ A,
                                                    const f16* __restrict__ B0,
                                                    const f16* __restrict__ B1,
                                                    f16* __restrict__ Ck, f16* __restrict__ Vt,
                                                    int K) {
    __shared__ __align__(16) char smem[16384];
    f16* Als = (f16*)smem;
    f16* Bls = (f16*)(smem + 8192);
    const int tid = threadIdx.x;
    const int w = tid >> 6, l = tid & 63;
    const int quad = l >> 4, ln = l & 15;
    const int m0 = blockIdx.y * 128, n0 = blockIdx.x * 128;
    const int wm = (w >> 1) * 64, wn = (w & 1) * 64;
    const int srow = l >> 2, scol = (l & 3) * 8;
    const f16* Bm = (n0 < 2048) ? B0 + (size_t)n0 * K : B1 + (size_t)(n0 - 2048) * K;

    f32x4 acc[4][4];
#pragma unroll
    for (int i = 0; i < 4; ++i)
#pragma unroll
        for (int j = 0; j < 4; ++j)
#pragma unroll
            for (int r = 0; r < 4; ++r) acc[i][j][r] = 0.f;

    for (int k0 = 0; k0 < K; k0 += 32) {
#pragma unroll
        for (int c = 0; c < 2; ++c) {
            const int ch = w + 4 * c;
            gld16(A + (size_t)(m0 + ch * 16 + srow) * K + (k0 + scol), &Als[ch * 512]);
            gld16(Bm + (size_t)(ch * 16 + srow) * K + (k0 + scol), &Bls[ch * 512]);
        }
        __syncthreads();
        f16x8 af[4], bf[4];
#pragma unroll
        for (int i = 0; i < 4; ++i) af[i] = *(const f16x8*)&Als[(wm + 16 * i + ln) * 32 + quad * 8];
#pragma unroll
        for (int j = 0; j < 4; ++j) bf[j] = *(const f16x8*)&Bls[(wn + 16 * j + ln) * 32 + quad * 8];
#pragma unroll
        for (int i = 0; i < 4; ++i)
#pragma unroll
            for (int j = 0; j < 4; ++j)
                acc[i][j] = __builtin_amdgcn_mfma_f32_16x16x32_f16(af[i], bf[j], acc[i][j], 0, 0, 0);
        __syncthreads();
    }
    const int p_w = (w >> 1) ? 16 : 0;
    f16* Cs = (f16*)smem;  // [32][136]
    const int bb = m0 >> 11;
    const int tb = m0 & 2047;
#pragma unroll
    for (int i = 0; i < 4; ++i) {
#pragma unroll
        for (int j = 0; j < 4; ++j)
#pragma unroll
            for (int r = 0; r < 4; ++r)
                Cs[(p_w + quad * 4 + r) * 136 + wn + 16 * j + ln] = (f16)acc[i][j][r];
        __syncthreads();
        if (n0 < 2048) {
#pragma unroll
            for (int k2 = 0; k2 < 2; ++k2) {
                int idx = k2 * 256 + tid;
                int pr = idx >> 4, c = idx & 15;
                int rg = m0 + 16 * i + (pr & 15) + ((pr & 16) ? 64 : 0);
                *(f16x8*)&Ck[(size_t)rg * 2048 + n0 + c * 8] = *(const f16x8*)&Cs[pr * 136 + c * 8];
            }
        } else {
#pragma unroll
            for (int it = 0; it < 2; ++it) {
                int idx = it * 256 + tid;          // 0..511
                int d = idx & 127, tc = (idx >> 7) & 1, g = idx >> 8;
                f16x8 v;
#pragma unroll
                for (int k = 0; k < 8; ++k) v[k] = Cs[(g * 16 + tc * 8 + k) * 136 + d];
                int t = tb + 16 * i + g * 64 + tc * 8;
                *(f16x8*)&Vt[((size_t)(bb * 2048 + (n0 - 2048) + d)) * 2048 + t] = v;
            }
        }
        __syncthreads();
    }
}

// ---------------------------------------------------------------- RMSNorm + RoPE (in place)
__global__ __launch_bounds__(256) void k_norm_rope(f16* __restrict__ q, f16* __restrict__ k,
                                                   const float* __restrict__ qw,
                                                   const float* __restrict__ kw) {
    const int gw = blockIdx.x * 4 + (threadIdx.x >> 6);
    const int l = threadIdx.x & 63;
    const int which = gw >> 16;
    const int rh = gw & 65535;
    const int row = rh >> 4, h = rh & 15;
    f16* p = which ? k : q;
    const float* wp = which ? kw : qw;
    const float scale = which ? 1.0f : 0.08838834764831843f;  // 1/sqrt(128) folded into q
    const size_t base = (size_t)row * DMODEL + h * 128;
    float xa = (float)p[base + l];
    float xb = (float)p[base + 64 + l];
    float ss = xa * xa + xb * xb;
#pragma unroll
    for (int off = 32; off > 0; off >>= 1) ss += __shfl_xor(ss, off);
    const float rms = rsqrtf(ss * (1.0f / 128.0f) + 1e-6f);
    const float na = xa * rms * wp[l];
    const float nb = xb * rms * wp[64 + l];
    const int t = row & 2047;
    const float freq = __expf((float)l * -0.1439115683121279f);  // ln(10000)/64
    const float ang = (float)t * freq;
    const float c = cosf(ang), s = sinf(ang);
    p[base + l]      = (f16)((na * c - nb * s) * scale);
    p[base + 64 + l] = (f16)((nb * c + na * s) * scale);
}

// ---------------------------------------------------------------- flash attention, causal, BM=64 BN=64
// S^T trick: S^T = K·Q^T so P lands in-register in 16x16x16 A-operand layout (no LDS roundtrip).
// grid (h, b, mtidx) = (16, 2, 32); mt = 31 - mtidx (heavy first, (h,b) XCD-local).
__global__ __launch_bounds__(256, 4) void k_flash(const f16* __restrict__ Q, const f16* __restrict__ K,
                                                  const f16* __restrict__ Vt, f16* __restrict__ O) {
    __shared__ f16 Kl[64 * 136];   // [t_k][d]
    __shared__ f16 Vl[128 * 72];   // [d][t_k]
    const int h = blockIdx.x, b = blockIdx.y, mt = 31 - blockIdx.z;
    const int tid = threadIdx.x, w = tid >> 6, l64 = tid & 63;
    const int quad = l64 >> 4, ln = l64 & 15;

    // Q fragments (B-operand of S^T mfma): lane ln holds Q[q=ln][k=quad*8+i]
    f16x8 qf[4];
    {
        const int tq = mt * 64 + w * 16 + ln;
        const f16* qp = Q + (size_t)(b * 2048 + tq) * DMODEL + h * 128 + quad * 8;
#pragma unroll
        for (int kc = 0; kc < 4; ++kc) qf[kc] = *(const f16x8*)(qp + kc * 32);
    }
    f32x4 oacc[8];
#pragma unroll
    for (int ot = 0; ot < 8; ++ot)
#pragma unroll
        for (int r = 0; r < 4; ++r) oacc[ot][r] = 0.f;
    float m_r = -INFINITY, l_r = 0.f;  // per-lane: row q = ln

    const f16* kbase = K + (size_t)(b * 2048) * DMODEL + h * 128;
    const f16* vbase = Vt + (size_t)(b * 2048 + h * 128) * 2048;

    f16x8 kr[4], vr[4];
#pragma unroll
    for (int c = 0; c < 4; ++c) {
        int idx = c * 256 + tid;
        kr[c] = *(const f16x8*)(kbase + (size_t)(idx >> 4) * DMODEL + (idx & 15) * 8);
        vr[c] = *(const f16x8*)(vbase + (size_t)(idx >> 3) * 2048 + (idx & 7) * 8);
    }

    for (int j = 0; j <= mt; ++j) {
        __syncthreads();
#pragma unroll
        for (int c = 0; c < 4; ++c) {
            int idx = c * 256 + tid;
            *(f16x8*)&Kl[(idx >> 4) * 136 + (idx & 15) * 8] = kr[c];
            *(f16x8*)&Vl[(idx >> 3) * 72 + (idx & 7) * 8] = vr[c];
        }
        __syncthreads();
        if (j < mt) {
#pragma unroll
            for (int c = 0; c < 4; ++c) {
                int idx = c * 256 + tid;
                kr[c] = *(const f16x8*)(kbase + (size_t)((j + 1) * 64 + (idx >> 4)) * DMODEL + (idx & 15) * 8);
                vr[c] = *(const f16x8*)(vbase + (size_t)(idx >> 3) * 2048 + (j + 1) * 64 + (idx & 7) * 8);
            }
        }
        // S^T = K Q^T : A-frag = K rows (t_k), B-frag = Q. C: row=t_k(quad*4+r), col=q(ln)
        f32x4 sacc[4];
#pragma unroll
        for (int nt = 0; nt < 4; ++nt)
#pragma unroll
            for (int r = 0; r < 4; ++r) sacc[nt][r] = 0.f;
#pragma unroll
        for (int nt = 0; nt < 4; ++nt)
#pragma unroll
            for (int kc = 0; kc < 4; ++kc) {
                f16x8 kf = *(const f16x8*)&Kl[(nt * 16 + ln) * 136 + kc * 32 + quad * 8];
                sacc[nt] = __builtin_amdgcn_mfma_f32_16x16x32_f16(kf, qf[kc], sacc[nt], 0, 0, 0);
            }
        if (j == mt) {  // diagonal: mask k > q
#pragma unroll
            for (int nt = 0; nt < 4; ++nt)
#pragma unroll
                for (int r = 0; r < 4; ++r)
                    if (nt * 16 + quad * 4 + r > w * 16 + ln) sacc[nt][r] = -INFINITY;
        }
        // online softmax: each lane owns its whole row (16 vals), reduce across quads only
        float mx = -INFINITY;
#pragma unroll
        for (int nt = 0; nt < 4; ++nt)
#pragma unroll
            for (int r = 0; r < 4; ++r) mx = fmaxf(mx, sacc[nt][r]);
        mx = fmaxf(mx, __shfl_xor(mx, 16));
        mx = fmaxf(mx, __shfl_xor(mx, 32));
        const float mn = fmaxf(m_r, mx);
        const float alpha = __expf(m_r - mn);
        m_r = mn;
        f16x4 pa[4];
        float s0 = 0.f;
#pragma unroll
        for (int nt = 0; nt < 4; ++nt)
#pragma unroll
            for (int r = 0; r < 4; ++r) {
                float pv = __expf(sacc[nt][r] - mn);
                s0 += pv;
                pa[nt][r] = (f16)pv;
            }
        s0 += __shfl_xor(s0, 16);
        s0 += __shfl_xor(s0, 32);
        l_r = l_r * alpha + s0;
        // rescale O rows (row index quad*4+r needs alpha of lane ln'=quad*4+r)
        float ar[4];
#pragma unroll
        for (int r = 0; r < 4; ++r) ar[r] = __shfl(alpha, (l64 & 48) | (quad * 4 + r));
#pragma unroll
        for (int ot = 0; ot < 8; ++ot)
#pragma unroll
            for (int r = 0; r < 4; ++r) oacc[ot][r] *= ar[r];
        // O += P @ V via 16x16x16 (P already in A-layout in registers)
#pragma unroll
        for (int nt = 0; nt < 4; ++nt)
#pragma unroll
            for (int ot = 0; ot < 8; ++ot) {
                f16x4 vf = *(const f16x4*)&Vl[(ot * 16 + ln) * 72 + nt * 16 + quad * 4];
                oacc[ot] = __builtin_amdgcn_mfma_f32_16x16x16f16(pa[nt], vf, oacc[ot], 0, 0, 0);
            }
    }
    const float inv = 1.0f / l_r;
    float ivr[4];
#pragma unroll
    for (int r = 0; r < 4; ++r) ivr[r] = __shfl(inv, (l64 & 48) | (quad * 4 + r));
    __syncthreads();
#pragma unroll
    for (int ot = 0; ot < 8; ++ot)
#pragma unroll
        for (int r = 0; r < 4; ++r)
            Kl[(w * 16 + quad * 4 + r) * 136 + ot * 16 + ln] = (f16)(oacc[ot][r] * ivr[r]);
    __syncthreads();
#pragma unroll
    for (int c = 0; c < 4; ++c) {
        int idx = c * 256 + tid;
        int row = idx >> 4, col8 = (idx & 15) * 8;
        *(f16x8*)&O[(size_t)(b * 2048 + mt * 64 + row) * DMODEL + h * 128 + col8] =
            *(const f16x8*)&Kl[row * 136 + col8];
    }
}

// ----------------------------------------------------------------
extern "C" void kernel_launch(void* const* d_in, const int* in_sizes, int n_in,
                              void* d_out, int out_size, void* d_ws, size_t ws_size,
                              hipStream_t stream) {
    const float* x    = (const float*)d_in[0];
    const float* qaw  = (const float*)d_in[2];
    const float* qbw  = (const float*)d_in[3];
    const float* kvaw = (const float*)d_in[4];
    const float* kbw  = (const float*)d_in[5];
    const float* vbw  = (const float*)d_in[6];
    const float* ow   = (const float*)d_in[7];
    const float* qnw  = (const float*)d_in[8];
    const float* knw  = (const float*)d_in[9];
    float* out = (float*)d_out;

    char* p = (char*)d_ws;
    auto alloc = [&](size_t elems) { f16* r = (f16*)p; p += elems * sizeof(f16); return r; };
    f16* xb   = alloc((size_t)BT * 2048);     // reused as vt
    f16* wo   = alloc((size_t)2048 * 2048);
    f16* wqa  = alloc((size_t)1024 * 2048);   // attn overlay starts here
    f16* wqb  = alloc((size_t)2048 * 1024);
    f16* wkva = alloc((size_t)512 * 2048);
    f16* wkb  = alloc((size_t)2048 * 512);
    f16* wvb  = alloc((size_t)2048 * 512);
    f16* qlat = alloc((size_t)BT * 1024);
    f16* kvb  = alloc((size_t)BT * 512);
    f16* qpre = alloc((size_t)BT * 2048);
    f16* kpre = alloc((size_t)BT * 2048);
    f16* vt   = xb;    // [b][d][t], written by k_gemm_kv after xb consumed
    f16* attn = wqa;   // overlays wqa..qlat (11.5M elems >= 8.4M), free post-GEMMs

    Cvt7 c;
    c.s[0] = x;    c.d[0] = xb;
    c.s[1] = qaw;  c.d[1] = wqa;
    c.s[2] = qbw;  c.d[2] = wqb;
    c.s[3] = kvaw; c.d[3] = wkva;
    c.s[4] = kbw;  c.d[4] = wkb;
    c.s[5] = vbw;  c.d[5] = wvb;
    c.s[6] = ow;   c.d[6] = wo;
    int sz4[7] = {BT * 2048 / 4, 1024 * 2048 / 4, 2048 * 1024 / 4, 512 * 2048 / 4,
                  2048 * 512 / 4, 2048 * 512 / 4, 2048 * 2048 / 4};
    c.off4[0] = 0;
    for (int i = 0; i < 7; ++i) c.off4[i + 1] = c.off4[i] + sz4[i];
    k_cvt7<<<(c.off4[7] + 255) / 256, 256, 0, stream>>>(c);

    dim3 blk(256);
    // qlat = xb@wqa^T ; kvb = xb@wkva^T  (merged)
    k_gemm_dual<<<dim3(1536 / 128, BT / 128), blk, 0, stream>>>(xb, wqa, wkva, qlat, kvb, 2048, 1024, 1024, 512);
    // qpre = qlat@wqb^T
    k_gemm_bt<f16><<<dim3(2048 / 128, BT / 128), blk, 0, stream>>>(qlat, wqb, qpre, BT, 2048, 1024);
    // kpre = kvb@wkb^T ; vt = transpose(kvb@wvb^T)  (merged)
    k_gemm_kv<<<dim3(4096 / 128, BT / 128), blk, 0, stream>>>(kvb, wkb, wvb, kpre, vt, 512);
    // rmsnorm + rope in place
    k_norm_rope<<<32768, 256, 0, stream>>>(qpre, kpre, qnw, knw);
    // flash attention
    k_flash<<<dim3(16, 2, 32), 256, 0, stream>>>(qpre, kpre, vt, attn);
    // out = attn@wo^T (fp32)
    k_gemm_bt<float><<<dim3(2048 / 128, BT / 128), blk, 0, stream>>>(attn, wo, out, BT, 2048, 2048);
}

// Round 4
// 389.855 us; speedup vs baseline: 1.3666x; 1.2111x over previous
//
#include <hip/hip_runtime.h>
#include <hip/hip_fp16.h>

typedef _Float16 f16;
typedef _Float16 f16x4 __attribute__((ext_vector_type(4)));
typedef _Float16 f16x8 __attribute__((ext_vector_type(8)));
typedef float f32x4 __attribute__((ext_vector_type(4)));

// B=2, T=2048, D=2048, NH=16, HD=128, Q_LAT=1024, KV_LAT=512
#define BT 4096
#define DMODEL 2048

__device__ __forceinline__ void gld16(const f16* g, f16* l) {
    __builtin_amdgcn_global_load_lds((const __attribute__((address_space(1))) void*)g,
                                     (__attribute__((address_space(3))) void*)l, 16, 0, 0);
}

// ---------------------------------------------------------------- fused fp32 -> fp16 (7 tensors, 1 launch)
struct Cvt7 {
    const float* s[7];
    f16* d[7];
    int off4[8];  // cumulative float4 counts
};
__global__ __launch_bounds__(256) void k_cvt7(Cvt7 c) {
    int i = blockIdx.x * 256 + threadIdx.x;
    if (i >= c.off4[7]) return;
    int seg = 0;
#pragma unroll
    for (int k = 1; k < 7; ++k) seg += (i >= c.off4[k]);
    int j = i - c.off4[seg];
    float4 v = ((const float4*)c.s[seg])[j];
    f16x4 h;
    h[0] = (f16)v.x; h[1] = (f16)v.y; h[2] = (f16)v.z; h[3] = (f16)v.w;
    ((f16x4*)c.d[seg])[j] = h;
}

// ---------------------------------------------------------------- GEMM (m97 structure)
// plain: C[M,N] = A[M,K] @ B[N,K]^T
template <typename CT>
__global__ __launch_bounds__(256, 3) void k_gemm_bt(const f16* __restrict__ A,
                                                    const f16* __restrict__ Bm,
                                                    CT* __restrict__ C,
                                                    int M, int N, int K) {
    __shared__ __align__(16) char smem[16384];
    f16* Als = (f16*)smem;
    f16* Bls = (f16*)(smem + 8192);
    const int tid = threadIdx.x;
    const int w = tid >> 6, l = tid & 63;
    const int quad = l >> 4, ln = l & 15;
    const int m0 = blockIdx.y * 128, n0 = blockIdx.x * 128;
    const int wm = (w >> 1) * 64, wn = (w & 1) * 64;
    const int srow = l >> 2, scol = (l & 3) * 8;

    f32x4 acc[4][4];
#pragma unroll
    for (int i = 0; i < 4; ++i)
#pragma unroll
        for (int j = 0; j < 4; ++j)
#pragma unroll
            for (int r = 0; r < 4; ++r) acc[i][j][r] = 0.f;

    for (int k0 = 0; k0 < K; k0 += 32) {
#pragma unroll
        for (int c = 0; c < 2; ++c) {
            const int ch = w + 4 * c;
            gld16(A + (size_t)(m0 + ch * 16 + srow) * K + (k0 + scol), &Als[ch * 512]);
            gld16(Bm + (size_t)(n0 + ch * 16 + srow) * K + (k0 + scol), &Bls[ch * 512]);
        }
        __syncthreads();
        f16x8 af[4], bf[4];
#pragma unroll
        for (int i = 0; i < 4; ++i) af[i] = *(const f16x8*)&Als[(wm + 16 * i + ln) * 32 + quad * 8];
#pragma unroll
        for (int j = 0; j < 4; ++j) bf[j] = *(const f16x8*)&Bls[(wn + 16 * j + ln) * 32 + quad * 8];
#pragma unroll
        for (int i = 0; i < 4; ++i)
#pragma unroll
            for (int j = 0; j < 4; ++j)
                acc[i][j] = __builtin_amdgcn_mfma_f32_16x16x32_f16(af[i], bf[j], acc[i][j], 0, 0, 0);
        __syncthreads();
    }
    const int p_w = (w >> 1) ? 16 : 0;
#pragma unroll
    for (int i = 0; i < 4; ++i) {
        if constexpr (sizeof(CT) == 2) {
            f16* Cs = (f16*)smem;  // [32][136]
#pragma unroll
            for (int j = 0; j < 4; ++j)
#pragma unroll
                for (int r = 0; r < 4; ++r)
                    Cs[(p_w + quad * 4 + r) * 136 + wn + 16 * j + ln] = (f16)acc[i][j][r];
            __syncthreads();
#pragma unroll
            for (int k2 = 0; k2 < 2; ++k2) {
                int idx = k2 * 256 + tid;
                int pr = idx >> 4, c = idx & 15;
                int rg = m0 + 16 * i + (pr & 15) + ((pr & 16) ? 64 : 0);
                *(f16x8*)&C[(size_t)rg * N + n0 + c * 8] = *(const f16x8*)&Cs[pr * 136 + c * 8];
            }
        } else {
            float* Cs = (float*)smem;  // [32][128]
#pragma unroll
            for (int j = 0; j < 4; ++j)
#pragma unroll
                for (int r = 0; r < 4; ++r)
                    Cs[(p_w + quad * 4 + r) * 128 + wn + 16 * j + ln] = acc[i][j][r];
            __syncthreads();
#pragma unroll
            for (int k2 = 0; k2 < 4; ++k2) {
                int idx = k2 * 256 + tid;
                int pr = idx >> 5, c = idx & 31;
                int rg = m0 + 16 * i + (pr & 15) + ((pr & 16) ? 64 : 0);
                *(float4*)&C[(size_t)rg * N + n0 + c * 4] = *(const float4*)&Cs[pr * 128 + c * 4];
            }
        }
        __syncthreads();
    }
}

// dual-B / dual-C: cols < nsplit -> C0 (ld0), else C1 (ld1). Both f16.
__global__ __launch_bounds__(256, 3) void k_gemm_dual(const f16* __restrict__ A,
                                                      const f16* __restrict__ B0,
                                                      const f16* __restrict__ B1,
                                                      f16* __restrict__ C0, f16* __restrict__ C1,
                                                      int K, int nsplit, int ld0, int ld1) {
    __shared__ __align__(16) char smem[16384];
    f16* Als = (f16*)smem;
    f16* Bls = (f16*)(smem + 8192);
    const int tid = threadIdx.x;
    const int w = tid >> 6, l = tid & 63;
    const int quad = l >> 4, ln = l & 15;
    const int m0 = blockIdx.y * 128, n0 = blockIdx.x * 128;
    const int wm = (w >> 1) * 64, wn = (w & 1) * 64;
    const int srow = l >> 2, scol = (l & 3) * 8;
    const f16* Bm = (n0 < nsplit) ? B0 + (size_t)n0 * K : B1 + (size_t)(n0 - nsplit) * K;

    f32x4 acc[4][4];
#pragma unroll
    for (int i = 0; i < 4; ++i)
#pragma unroll
        for (int j = 0; j < 4; ++j)
#pragma unroll
            for (int r = 0; r < 4; ++r) acc[i][j][r] = 0.f;

    for (int k0 = 0; k0 < K; k0 += 32) {
#pragma unroll
        for (int c = 0; c < 2; ++c) {
            const int ch = w + 4 * c;
            gld16(A + (size_t)(m0 + ch * 16 + srow) * K + (k0 + scol), &Als[ch * 512]);
            gld16(Bm + (size_t)(ch * 16 + srow) * K + (k0 + scol), &Bls[ch * 512]);
        }
        __syncthreads();
        f16x8 af[4], bf[4];
#pragma unroll
        for (int i = 0; i < 4; ++i) af[i] = *(const f16x8*)&Als[(wm + 16 * i + ln) * 32 + quad * 8];
#pragma unroll
        for (int j = 0; j < 4; ++j) bf[j] = *(const f16x8*)&Bls[(wn + 16 * j + ln) * 32 + quad * 8];
#pragma unroll
        for (int i = 0; i < 4; ++i)
#pragma unroll
            for (int j = 0; j < 4; ++j)
                acc[i][j] = __builtin_amdgcn_mfma_f32_16x16x32_f16(af[i], bf[j], acc[i][j], 0, 0, 0);
        __syncthreads();
    }
    f16* Cd; int ldc, cb;
    if (n0 < nsplit) { Cd = C0; ldc = ld0; cb = n0; }
    else             { Cd = C1; ldc = ld1; cb = n0 - nsplit; }
    const int p_w = (w >> 1) ? 16 : 0;
    f16* Cs = (f16*)smem;  // [32][136]
#pragma unroll
    for (int i = 0; i < 4; ++i) {
#pragma unroll
        for (int j = 0; j < 4; ++j)
#pragma unroll
            for (int r = 0; r < 4; ++r)
                Cs[(p_w + quad * 4 + r) * 136 + wn + 16 * j + ln] = (f16)acc[i][j][r];
        __syncthreads();
#pragma unroll
        for (int k2 = 0; k2 < 2; ++k2) {
            int idx = k2 * 256 + tid;
            int pr = idx >> 4, c = idx & 15;
            int rg = m0 + 16 * i + (pr & 15) + ((pr & 16) ? 64 : 0);
            *(f16x8*)&Cd[(size_t)rg * ldc + cb + c * 8] = *(const f16x8*)&Cs[pr * 136 + c * 8];
        }
        __syncthreads();
    }
}

// k/v GEMM: cols<2048 -> kpre normal; cols>=2048 -> V written TRANSPOSED into vt[(b*2048+d)*2048 + t]
__global__ __launch_bounds__(256, 3) void k_gemm_kv(const f16* __restrict__ A,
                                                    const f16* __restrict__ B0,
                                                    const f16* __restrict__ B1,
                                                    f16* __restrict__ Ck, f16* __restrict__ Vt,
                                                    int K) {
    __shared__ __align__(16) char smem[16384];
    f16* Als = (f16*)smem;
    f16* Bls = (f16*)(smem + 8192);
    const int tid = threadIdx.x;
    const int w = tid >> 6, l = tid & 63;
    const int quad = l >> 4, ln = l & 15;
    const int m0 = blockIdx.y * 128, n0 = blockIdx.x * 128;
    const int wm = (w >> 1) * 64, wn = (w & 1) * 64;
    const int srow = l >> 2, scol = (l & 3) * 8;
    const f16* Bm = (n0 < 2048) ? B0 + (size_t)n0 * K : B1 + (size_t)(n0 - 2048) * K;

    f32x4 acc[4][4];
#pragma unroll
    for (int i = 0; i < 4; ++i)
#pragma unroll
        for (int j = 0; j < 4; ++j)
#pragma unroll
            for (int r = 0; r < 4; ++r) acc[i][j][r] = 0.f;

    for (int k0 = 0; k0 < K; k0 += 32) {
#pragma unroll
        for (int c = 0; c < 2; ++c) {
            const int ch = w + 4 * c;
            gld16(A + (size_t)(m0 + ch * 16 + srow) * K + (k0 + scol), &Als[ch * 512]);
            gld16(Bm + (size_t)(ch * 16 + srow) * K + (k0 + scol), &Bls[ch * 512]);
        }
        __syncthreads();
        f16x8 af[4], bf[4];
#pragma unroll
        for (int i = 0; i < 4; ++i) af[i] = *(const f16x8*)&Als[(wm + 16 * i + ln) * 32 + quad * 8];
#pragma unroll
        for (int j = 0; j < 4; ++j) bf[j] = *(const f16x8*)&Bls[(wn + 16 * j + ln) * 32 + quad * 8];
#pragma unroll
        for (int i = 0; i < 4; ++i)
#pragma unroll
            for (int j = 0; j < 4; ++j)
                acc[i][j] = __builtin_amdgcn_mfma_f32_16x16x32_f16(af[i], bf[j], acc[i][j], 0, 0, 0);
        __syncthreads();
    }
    const int p_w = (w >> 1) ? 16 : 0;
    f16* Cs = (f16*)smem;  // [32][136]
    const int bb = m0 >> 11;
    const int tb = m0 & 2047;
#pragma unroll
    for (int i = 0; i < 4; ++i) {
#pragma unroll
        for (int j = 0; j < 4; ++j)
#pragma unroll
            for (int r = 0; r < 4; ++r)
                Cs[(p_w + quad * 4 + r) * 136 + wn + 16 * j + ln] = (f16)acc[i][j][r];
        __syncthreads();
        if (n0 < 2048) {
#pragma unroll
            for (int k2 = 0; k2 < 2; ++k2) {
                int idx = k2 * 256 + tid;
                int pr = idx >> 4, c = idx & 15;
                int rg = m0 + 16 * i + (pr & 15) + ((pr & 16) ? 64 : 0);
                *(f16x8*)&Ck[(size_t)rg * 2048 + n0 + c * 8] = *(const f16x8*)&Cs[pr * 136 + c * 8];
            }
        } else {
#pragma unroll
            for (int it = 0; it < 2; ++it) {
                int idx = it * 256 + tid;          // 0..511
                int d = idx & 127, tc = (idx >> 7) & 1, g = idx >> 8;
                f16x8 v;
#pragma unroll
                for (int k = 0; k < 8; ++k) v[k] = Cs[(g * 16 + tc * 8 + k) * 136 + d];
                int t = tb + 16 * i + g * 64 + tc * 8;
                *(f16x8*)&Vt[((size_t)(bb * 2048 + (n0 - 2048) + d)) * 2048 + t] = v;
            }
        }
        __syncthreads();
    }
}

// ---------------------------------------------------------------- RMSNorm + RoPE (in place)
__global__ __launch_bounds__(256) void k_norm_rope(f16* __restrict__ q, f16* __restrict__ k,
                                                   const float* __restrict__ qw,
                                                   const float* __restrict__ kw) {
    const int gw = blockIdx.x * 4 + (threadIdx.x >> 6);
    const int l = threadIdx.x & 63;
    const int which = gw >> 16;
    const int rh = gw & 65535;
    const int row = rh >> 4, h = rh & 15;
    f16* p = which ? k : q;
    const float* wp = which ? kw : qw;
    const float scale = which ? 1.0f : 0.08838834764831843f;  // 1/sqrt(128) folded into q
    const size_t base = (size_t)row * DMODEL + h * 128;
    float xa = (float)p[base + l];
    float xb = (float)p[base + 64 + l];
    float ss = xa * xa + xb * xb;
#pragma unroll
    for (int off = 32; off > 0; off >>= 1) ss += __shfl_xor(ss, off);
    const float rms = rsqrtf(ss * (1.0f / 128.0f) + 1e-6f);
    const float na = xa * rms * wp[l];
    const float nb = xb * rms * wp[64 + l];
    const int t = row & 2047;
    const float freq = __expf((float)l * -0.1439115683121279f);  // ln(10000)/64
    const float ang = (float)t * freq;
    const float c = cosf(ang), s = sinf(ang);
    p[base + l]      = (f16)((na * c - nb * s) * scale);
    p[base + 64 + l] = (f16)((nb * c + na * s) * scale);
}

// ---------------------------------------------------------------- flash attention, causal, BM=64 BN=64
// S^T trick: S^T = K·Q^T so P lands in-register in 16x16x16 A-operand layout (no LDS roundtrip).
// grid (h, b, mtidx) = (16, 2, 32); mt = 31 - mtidx (heavy first, (h,b) XCD-local).
// launch_bounds(256,3): 170 regs/wave -> no scratch spill (287 MB of spill traffic at (256,4)).
__global__ __launch_bounds__(256, 3) void k_flash(const f16* __restrict__ Q, const f16* __restrict__ K,
                                                  const f16* __restrict__ Vt, f16* __restrict__ O) {
    __shared__ f16 Kl[64 * 136];   // [t_k][d]
    __shared__ f16 Vl[128 * 72];   // [d][t_k]
    const int h = blockIdx.x, b = blockIdx.y, mt = 31 - blockIdx.z;
    const int tid = threadIdx.x, w = tid >> 6, l64 = tid & 63;
    const int quad = l64 >> 4, ln = l64 & 15;

    // Q fragments (B-operand of S^T mfma): lane ln holds Q[q=ln][k=quad*8+i]
    f16x8 qf[4];
    {
        const int tq = mt * 64 + w * 16 + ln;
        const f16* qp = Q + (size_t)(b * 2048 + tq) * DMODEL + h * 128 + quad * 8;
#pragma unroll
        for (int kc = 0; kc < 4; ++kc) qf[kc] = *(const f16x8*)(qp + kc * 32);
    }
    f32x4 oacc[8];
#pragma unroll
    for (int ot = 0; ot < 8; ++ot)
#pragma unroll
        for (int r = 0; r < 4; ++r) oacc[ot][r] = 0.f;
    float m_r = -INFINITY, l_r = 0.f;  // per-lane: row q = ln

    const f16* kbase = K + (size_t)(b * 2048) * DMODEL + h * 128;
    const f16* vbase = Vt + (size_t)(b * 2048 + h * 128) * 2048;

    f16x8 kr[4], vr[4];
#pragma unroll
    for (int c = 0; c < 4; ++c) {
        int idx = c * 256 + tid;
        kr[c] = *(const f16x8*)(kbase + (size_t)(idx >> 4) * DMODEL + (idx & 15) * 8);
        vr[c] = *(const f16x8*)(vbase + (size_t)(idx >> 3) * 2048 + (idx & 7) * 8);
    }

    for (int j = 0; j <= mt; ++j) {
        __syncthreads();
#pragma unroll
        for (int c = 0; c < 4; ++c) {
            int idx = c * 256 + tid;
            *(f16x8*)&Kl[(idx >> 4) * 136 + (idx & 15) * 8] = kr[c];
            *(f16x8*)&Vl[(idx >> 3) * 72 + (idx & 7) * 8] = vr[c];
        }
        __syncthreads();
        if (j < mt) {
#pragma unroll
            for (int c = 0; c < 4; ++c) {
                int idx = c * 256 + tid;
                kr[c] = *(const f16x8*)(kbase + (size_t)((j + 1) * 64 + (idx >> 4)) * DMODEL + (idx & 15) * 8);
                vr[c] = *(const f16x8*)(vbase + (size_t)(idx >> 3) * 2048 + (j + 1) * 64 + (idx & 7) * 8);
            }
        }
        // S^T = K Q^T : A-frag = K rows (t_k), B-frag = Q. C: row=t_k(quad*4+r), col=q(ln)
        f32x4 sacc[4];
#pragma unroll
        for (int nt = 0; nt < 4; ++nt)
#pragma unroll
            for (int r = 0; r < 4; ++r) sacc[nt][r] = 0.f;
#pragma unroll
        for (int nt = 0; nt < 4; ++nt)
#pragma unroll
            for (int kc = 0; kc < 4; ++kc) {
                f16x8 kf = *(const f16x8*)&Kl[(nt * 16 + ln) * 136 + kc * 32 + quad * 8];
                sacc[nt] = __builtin_amdgcn_mfma_f32_16x16x32_f16(kf, qf[kc], sacc[nt], 0, 0, 0);
            }
        if (j == mt) {  // diagonal: mask k > q
#pragma unroll
            for (int nt = 0; nt < 4; ++nt)
#pragma unroll
                for (int r = 0; r < 4; ++r)
                    if (nt * 16 + quad * 4 + r > w * 16 + ln) sacc[nt][r] = -INFINITY;
        }
        // online softmax: each lane owns its whole row (16 vals), reduce across quads only
        float mx = -INFINITY;
#pragma unroll
        for (int nt = 0; nt < 4; ++nt)
#pragma unroll
            for (int r = 0; r < 4; ++r) mx = fmaxf(mx, sacc[nt][r]);
        mx = fmaxf(mx, __shfl_xor(mx, 16));
        mx = fmaxf(mx, __shfl_xor(mx, 32));
        const float mn = fmaxf(m_r, mx);
        const float alpha = __expf(m_r - mn);
        m_r = mn;
        f16x4 pa[4];
        float s0 = 0.f;
#pragma unroll
        for (int nt = 0; nt < 4; ++nt)
#pragma unroll
            for (int r = 0; r < 4; ++r) {
                float pv = __expf(sacc[nt][r] - mn);
                s0 += pv;
                pa[nt][r] = (f16)pv;
            }
        s0 += __shfl_xor(s0, 16);
        s0 += __shfl_xor(s0, 32);
        l_r = l_r * alpha + s0;
        // rescale O rows (row index quad*4+r needs alpha of lane ln'=quad*4+r)
        float ar[4];
#pragma unroll
        for (int r = 0; r < 4; ++r) ar[r] = __shfl(alpha, (l64 & 48) | (quad * 4 + r));
#pragma unroll
        for (int ot = 0; ot < 8; ++ot)
#pragma unroll
            for (int r = 0; r < 4; ++r) oacc[ot][r] *= ar[r];
        // O += P @ V via 16x16x16 (P already in A-layout in registers)
#pragma unroll
        for (int nt = 0; nt < 4; ++nt)
#pragma unroll
            for (int ot = 0; ot < 8; ++ot) {
                f16x4 vf = *(const f16x4*)&Vl[(ot * 16 + ln) * 72 + nt * 16 + quad * 4];
                oacc[ot] = __builtin_amdgcn_mfma_f32_16x16x16f16(pa[nt], vf, oacc[ot], 0, 0, 0);
            }
    }
    const float inv = 1.0f / l_r;
    float ivr[4];
#pragma unroll
    for (int r = 0; r < 4; ++r) ivr[r] = __shfl(inv, (l64 & 48) | (quad * 4 + r));
    __syncthreads();
#pragma unroll
    for (int ot = 0; ot < 8; ++ot)
#pragma unroll
        for (int r = 0; r < 4; ++r)
            Kl[(w * 16 + quad * 4 + r) * 136 + ot * 16 + ln] = (f16)(oacc[ot][r] * ivr[r]);
    __syncthreads();
#pragma unroll
    for (int c = 0; c < 4; ++c) {
        int idx = c * 256 + tid;
        int row = idx >> 4, col8 = (idx & 15) * 8;
        *(f16x8*)&O[(size_t)(b * 2048 + mt * 64 + row) * DMODEL + h * 128 + col8] =
            *(const f16x8*)&Kl[row * 136 + col8];
    }
}

// ----------------------------------------------------------------
extern "C" void kernel_launch(void* const* d_in, const int* in_sizes, int n_in,
                              void* d_out, int out_size, void* d_ws, size_t ws_size,
                              hipStream_t stream) {
    const float* x    = (const float*)d_in[0];
    const float* qaw  = (const float*)d_in[2];
    const float* qbw  = (const float*)d_in[3];
    const float* kvaw = (const float*)d_in[4];
    const float* kbw  = (const float*)d_in[5];
    const float* vbw  = (const float*)d_in[6];
    const float* ow   = (const float*)d_in[7];
    const float* qnw  = (const float*)d_in[8];
    const float* knw  = (const float*)d_in[9];
    float* out = (float*)d_out;

    char* p = (char*)d_ws;
    auto alloc = [&](size_t elems) { f16* r = (f16*)p; p += elems * sizeof(f16); return r; };
    f16* xb   = alloc((size_t)BT * 2048);     // reused as vt
    f16* wo   = alloc((size_t)2048 * 2048);
    f16* wqa  = alloc((size_t)1024 * 2048);   // attn overlay starts here
    f16* wqb  = alloc((size_t)2048 * 1024);
    f16* wkva = alloc((size_t)512 * 2048);
    f16* wkb  = alloc((size_t)2048 * 512);
    f16* wvb  = alloc((size_t)2048 * 512);
    f16* qlat = alloc((size_t)BT * 1024);
    f16* kvb  = alloc((size_t)BT * 512);
    f16* qpre = alloc((size_t)BT * 2048);
    f16* kpre = alloc((size_t)BT * 2048);
    f16* vt   = xb;    // [b][d][t], written by k_gemm_kv after xb consumed
    f16* attn = wqa;   // overlays wqa..qlat, free post-GEMMs

    Cvt7 c;
    c.s[0] = x;    c.d[0] = xb;
    c.s[1] = qaw;  c.d[1] = wqa;
    c.s[2] = qbw;  c.d[2] = wqb;
    c.s[3] = kvaw; c.d[3] = wkva;
    c.s[4] = kbw;  c.d[4] = wkb;
    c.s[5] = vbw;  c.d[5] = wvb;
    c.s[6] = ow;   c.d[6] = wo;
    int sz4[7] = {BT * 2048 / 4, 1024 * 2048 / 4, 2048 * 1024 / 4, 512 * 2048 / 4,
                  2048 * 512 / 4, 2048 * 512 / 4, 2048 * 2048 / 4};
    c.off4[0] = 0;
    for (int i = 0; i < 7; ++i) c.off4[i + 1] = c.off4[i] + sz4[i];
    k_cvt7<<<(c.off4[7] + 255) / 256, 256, 0, stream>>>(c);

    dim3 blk(256);
    // qlat = xb@wqa^T ; kvb = xb@wkva^T  (merged)
    k_gemm_dual<<<dim3(1536 / 128, BT / 128), blk, 0, stream>>>(xb, wqa, wkva, qlat, kvb, 2048, 1024, 1024, 512);
    // qpre = qlat@wqb^T
    k_gemm_bt<f16><<<dim3(2048 / 128, BT / 128), blk, 0, stream>>>(qlat, wqb, qpre, BT, 2048, 1024);
    // kpre = kvb@wkb^T ; vt = transpose(kvb@wvb^T)  (merged)
    k_gemm_kv<<<dim3(4096 / 128, BT / 128), blk, 0, stream>>>(kvb, wkb, wvb, kpre, vt, 512);
    // rmsnorm + rope in place
    k_norm_rope<<<32768, 256, 0, stream>>>(qpre, kpre, qnw, knw);
    // flash attention
    k_flash<<<dim3(16, 2, 32), 256, 0, stream>>>(qpre, kpre, vt, attn);
    // out = attn@wo^T (fp32)
    k_gemm_bt<float><<<dim3(2048 / 128, BT / 128), blk, 0, stream>>>(attn, wo, out, BT, 2048, 2048);
}